// Round 1
// baseline (636.011 us; speedup 1.0000x reference)
//
#include <hip/hip_runtime.h>

typedef unsigned short u16;
typedef __attribute__((ext_vector_type(8))) __bf16 bf16x8;
typedef __attribute__((ext_vector_type(4))) float f32x4;

#define NWIN 4096
#define NTOK 64
#define DIM 256
#define NH 8
#define HD 32
#define SCALE 0.17677669529663687f

// workspace layout (bytes)
#define WSB_OFF   0ull               // attn-out bf16 [NWIN*64][256]  : 134217728 B
#define WQKVT_OFF 134217728ull       // [768][256] bf16, pre-swizzled : 393216 B
#define WPT_OFF   134610944ull       // [256][256] bf16, linear       : 131072 B
#define BIAS_OFF  134742016ull       // [8][64][64] f32               : 131072 B

__device__ __forceinline__ u16 f2bf(float f) {
  __bf16 h = (__bf16)f;
  return __builtin_bit_cast(u16, h);
}

__device__ __forceinline__ void gload16(const void* g, void* l) {
  __builtin_amdgcn_global_load_lds(
      (const __attribute__((address_space(1))) unsigned int*)g,
      (__attribute__((address_space(3))) unsigned int*)l, 16, 0, 0);
}

__device__ __forceinline__ f32x4 mfma16(bf16x8 a, bf16x8 b, f32x4 c) {
  return __builtin_amdgcn_mfma_f32_16x16x32_bf16(a, b, c, 0, 0, 0);
}

// ---------------------------------------------------------------------------
// prep: transpose+convert weights to bf16 (wqkvT pre-swizzled within each
// 64B k-chunk so that the fused kernel's linear global_load_lds + XOR'd
// ds_read_b128 is conflict-reduced), and pregather the relative-position
// bias into [8][64][64] f32.
// ---------------------------------------------------------------------------
__global__ __launch_bounds__(256) void prep_kernel(
    const float* __restrict__ wq, const float* __restrict__ wkv,
    const float* __restrict__ wp, const float* __restrict__ table,
    u16* __restrict__ wqkvT, u16* __restrict__ wpT, float* __restrict__ biasf)
{
  int i = blockIdx.x * 256 + threadIdx.x;
  if (i < 196608) {                      // wqkvT: [n=768][k=256]
    int n = i >> 8, k = i & 255;
    float v = (n < 256) ? wq[k * 256 + n] : wkv[k * 512 + (n - 256)];
    // pre-swizzle: within each 32-element k-chunk, XOR element index bits 3-4
    // with ((n>>1)&3) so LDS-linear copy + swizzled read is conflict-light.
    int idx = n * 256 + (k & ~31) + ((k & 31) ^ (((n >> 1) & 3) << 3));
    wqkvT[idx] = f2bf(v);
  } else if (i < 262144) {               // wpT: [n=256][k=256], linear
    int j = i - 196608;
    int n = j >> 8, k = j & 255;
    wpT[n * 256 + k] = f2bf(wp[k * 256 + n]);
  } else if (i < 294912) {               // bias: [h=8][n=64][m=64]
    int j = i - 262144;
    int h = j >> 12, n = (j >> 6) & 63, m = j & 63;
    int dr = (n >> 3) - (m >> 3) + 7;
    int dc = (n & 7) - (m & 7) + 7;
    biasf[j] = table[(dr * 15 + dc) * 8 + h];
  }
}

// ---------------------------------------------------------------------------
// fused kernel: per window (1 block, 4 waves):
//   phase 1: stage x[64][256] fp32 -> bf16 LDS (swizzled)
//   phase 2: qkv = x @ [wq|wkv] + bias (scale folded into q), into LDS
//            weights double-buffered via global_load_lds, BK=32
//   phase 3: per head (2 heads/wave): S=QK^T + bias, wave-parallel softmax,
//            P via LDS (swizzled), O = P@V -> global bf16 [token][256]
// ---------------------------------------------------------------------------
__device__ __forceinline__ void stage_b(const u16* __restrict__ wqkvT,
                                        char* Bt, int buf, int it,
                                        int w, int lane) {
  int nt6 = it >> 3, ks8 = it & 7;
#pragma unroll
  for (int i = 0; i < 2; ++i) {
    int o = (w * 2 + i) * 1024 + lane * 16;
    int row = o >> 6, kb = o & 63;
    gload16((const char*)wqkvT + (size_t)(nt6 * 128 + row) * 512 + ks8 * 64 + kb,
            Bt + buf * 8192 + (w * 2 + i) * 1024);
  }
}

__global__ __launch_bounds__(256) void kf_kernel(
    const float* __restrict__ x, const u16* __restrict__ wqkvT,
    const float* __restrict__ bq, const float* __restrict__ bkv,
    const float* __restrict__ biasf, u16* __restrict__ attnout)
{
  __shared__ char smem[147456];
  char* xA  = smem;           // 32KB: x window bf16 [64][256], swz (t&7)<<4; reused as P
  char* qkv = smem + 32768;   // 96KB: [8][3][64][32] bf16, swz ((t>>1)&3)<<4
  char* Bt  = smem + 131072;  // 16KB: 2 x [128][32] bf16 weight tiles

  const int tid  = threadIdx.x;
  const int lane = tid & 63;
  const int w    = tid >> 6;
  const int c    = lane & 15;
  const int s4   = lane >> 4;
  const int b    = blockIdx.x;
  const f32x4 fzero = {0.f, 0.f, 0.f, 0.f};

  // ---- phase 1: stage x (fp32 -> bf16, swizzled) ----
  {
    const float* xw = x + (size_t)b * (NTOK * DIM);
#pragma unroll
    for (int it = 0; it < 16; ++it) {
      int e = (it * 256 + tid) * 4;
      int t = e >> 8, k = e & 255;
      float4 v = *(const float4*)(xw + e);
      ushort4 pk;
      pk.x = f2bf(v.x); pk.y = f2bf(v.y); pk.z = f2bf(v.z); pk.w = f2bf(v.w);
      *(ushort4*)(xA + ((t * 512 + k * 2) ^ ((t & 7) << 4))) = pk;
    }
  }

  // ---- phase 2: projection ----
  stage_b(wqkvT, Bt, 0, 0, w, lane);
  __syncthreads();   // drains x ds_writes + first weight stage

  for (int nt6 = 0; nt6 < 6; ++nt6) {
    f32x4 acc[4][2];
#pragma unroll
    for (int mt = 0; mt < 4; ++mt) { acc[mt][0] = fzero; acc[mt][1] = fzero; }

    for (int ks8 = 0; ks8 < 8; ++ks8) {
      int it = nt6 * 8 + ks8;
      if (it + 1 < 48) stage_b(wqkvT, Bt, (it + 1) & 1, it + 1, w, lane);
      const char* bb = Bt + (it & 1) * 8192;
      bf16x8 af[4];
#pragma unroll
      for (int mt = 0; mt < 4; ++mt) {
        int t = mt * 16 + c;
        af[mt] = *(const bf16x8*)(xA + ((t * 512 + ks8 * 64 + s4 * 16) ^ ((t & 7) << 4)));
      }
#pragma unroll
      for (int nf = 0; nf < 2; ++nf) {
        int n = w * 32 + nf * 16 + c;
        bf16x8 bfr = *(const bf16x8*)(bb + n * 64 + ((s4 * 16) ^ (((n >> 1) & 3) << 4)));
#pragma unroll
        for (int mt = 0; mt < 4; ++mt) acc[mt][nf] = mfma16(af[mt], bfr, acc[mt][nf]);
      }
      __syncthreads();
    }
    // epilogue -> qkv LDS (bias add; scale folded into q)
#pragma unroll
    for (int nf = 0; nf < 2; ++nf) {
      int col = nt6 * 128 + w * 32 + nf * 16 + c;
      float bias = (col < 256) ? bq[col] : bkv[col - 256];
      float sc = (col < 256) ? SCALE : 1.0f;
      int which = col >> 8, rem = col & 255, h = rem >> 5, d = rem & 31;
      char* base = qkv + (h * 3 + which) * 4096;
#pragma unroll
      for (int mt = 0; mt < 4; ++mt)
#pragma unroll
        for (int q = 0; q < 4; ++q) {
          int t = mt * 16 + s4 * 4 + q;
          *(u16*)(base + ((t * 64 + d * 2) ^ (((t >> 1) & 3) << 4))) =
              f2bf((acc[mt][nf][q] + bias) * sc);
        }
    }
  }
  __syncthreads();   // all qkv visible to all waves

  // ---- phase 3: attention (wave w -> heads 2w, 2w+1) ----
#pragma unroll 1
  for (int hi = 0; hi < 2; ++hi) {
    const int h = w * 2 + hi;
    const char* Qb = qkv + (h * 3 + 0) * 4096;
    const char* Kb = qkv + (h * 3 + 1) * 4096;
    const char* Vb = qkv + (h * 3 + 2) * 4096;

    bf16x8 aq[4], bk[4];
#pragma unroll
    for (int mt = 0; mt < 4; ++mt) {
      int t = mt * 16 + c;
      int off = (t * 64 + s4 * 16) ^ (((t >> 1) & 3) << 4);
      aq[mt] = *(const bf16x8*)(Qb + off);
      bk[mt] = *(const bf16x8*)(Kb + off);
    }
    f32x4 sa[4][4];
#pragma unroll
    for (int mt = 0; mt < 4; ++mt)
#pragma unroll
      for (int nt = 0; nt < 4; ++nt)
        sa[mt][nt] = mfma16(aq[mt], bk[nt], fzero);

    // bias add (S element: row n = q-token, col m = k-token)
    const float* bh = biasf + h * 4096;
#pragma unroll
    for (int mt = 0; mt < 4; ++mt)
#pragma unroll
      for (int q = 0; q < 4; ++q) {
        int n = mt * 16 + s4 * 4 + q;
#pragma unroll
        for (int nt = 0; nt < 4; ++nt)
          sa[mt][nt][q] += bh[n * 64 + nt * 16 + c];
      }

    // wave-parallel softmax over m (4 local + shfl_xor over 16-lane col group)
    float inv[4][4];
#pragma unroll
    for (int mt = 0; mt < 4; ++mt)
#pragma unroll
      for (int q = 0; q < 4; ++q) {
        float v = fmaxf(fmaxf(sa[mt][0][q], sa[mt][1][q]),
                        fmaxf(sa[mt][2][q], sa[mt][3][q]));
        v = fmaxf(v, __shfl_xor(v, 1));
        v = fmaxf(v, __shfl_xor(v, 2));
        v = fmaxf(v, __shfl_xor(v, 4));
        v = fmaxf(v, __shfl_xor(v, 8));
        float s0 = 0.f;
#pragma unroll
        for (int nt = 0; nt < 4; ++nt) {
          float p = __expf(sa[mt][nt][q] - v);
          sa[mt][nt][q] = p;
          s0 += p;
        }
        s0 += __shfl_xor(s0, 1);
        s0 += __shfl_xor(s0, 2);
        s0 += __shfl_xor(s0, 4);
        s0 += __shfl_xor(s0, 8);
        inv[mt][q] = __builtin_amdgcn_rcpf(s0);
      }

    // write P (bf16, normalized) to per-wave LDS buffer (reuses xA area)
    char* Pb = xA + w * 8192;
#pragma unroll
    for (int mt = 0; mt < 4; ++mt)
#pragma unroll
      for (int q = 0; q < 4; ++q) {
        int n = mt * 16 + s4 * 4 + q;
#pragma unroll
        for (int nt = 0; nt < 4; ++nt) {
          int m = nt * 16 + c;
          *(u16*)(Pb + ((n * 128 + m * 2) ^ ((n & 7) << 4))) =
              f2bf(sa[mt][nt][q] * inv[mt][q]);
        }
      }

    // O = P @ V
    f32x4 oa[4][2];
#pragma unroll
    for (int mt = 0; mt < 4; ++mt) { oa[mt][0] = fzero; oa[mt][1] = fzero; }
#pragma unroll
    for (int kk = 0; kk < 2; ++kk) {
      bf16x8 ap[4];
#pragma unroll
      for (int mt = 0; mt < 4; ++mt) {
        int n = mt * 16 + c;
        ap[mt] = *(const bf16x8*)(Pb + ((n * 128 + kk * 64 + s4 * 16) ^ ((n & 7) << 4)));
      }
#pragma unroll
      for (int nt2 = 0; nt2 < 2; ++nt2) {
        bf16x8 bv;
#pragma unroll
        for (int j = 0; j < 8; ++j) {
          int tv = kk * 32 + s4 * 8 + j;
          bv[j] = *(const __bf16*)(Vb + ((tv * 64 + (nt2 * 16 + c) * 2) ^ (((tv >> 1) & 3) << 4)));
        }
#pragma unroll
        for (int mt = 0; mt < 4; ++mt) oa[mt][nt2] = mfma16(ap[mt], bv, oa[mt][nt2]);
      }
    }

    // write O -> attnout[token][h*32+d]
    u16* ow = attnout + (size_t)b * (NTOK * DIM) + h * 32;
#pragma unroll
    for (int mt = 0; mt < 4; ++mt)
#pragma unroll
      for (int nt2 = 0; nt2 < 2; ++nt2)
#pragma unroll
        for (int q = 0; q < 4; ++q) {
          int t = mt * 16 + s4 * 4 + q;
          int d = nt2 * 16 + c;
          ow[t * DIM + d] = f2bf(oa[mt][nt2][q]);
        }
  }
}

// ---------------------------------------------------------------------------
// output projection: out = attnout(bf16) @ wp + bp, fp32 out.
// m97-style: 128x128 tile, BK=64, global_load_lds staging, 4 waves 2x2.
// ---------------------------------------------------------------------------
__global__ __launch_bounds__(256) void proj_kernel(
    const u16* __restrict__ A, const u16* __restrict__ wpT,
    const float* __restrict__ bp, float* __restrict__ out)
{
  __shared__ char smem[32768];
  char* As = smem;
  char* Bs = smem + 16384;
  const int tid = threadIdx.x, lane = tid & 63, w = tid >> 6;
  const int c = lane & 15, s4 = lane >> 4;
  const int m0 = (int)(blockIdx.x >> 1) * 128;
  const int n0 = (int)(blockIdx.x & 1) * 128;
  const int wr = w >> 1, wc = w & 1;
  const f32x4 fzero = {0.f, 0.f, 0.f, 0.f};

  f32x4 acc[4][4];
#pragma unroll
  for (int mt = 0; mt < 4; ++mt)
#pragma unroll
    for (int nt = 0; nt < 4; ++nt) acc[mt][nt] = fzero;

  for (int ks = 0; ks < 4; ++ks) {
    __syncthreads();
#pragma unroll
    for (int i = 0; i < 4; ++i) {
      int o = (w * 4 + i) * 1024 + lane * 16;
      int r = o >> 7, kb = o & 127;
      gload16((const char*)A + ((size_t)(m0 + r) * 256 + ks * 64) * 2 + kb,
              As + (w * 4 + i) * 1024);
      gload16((const char*)wpT + ((size_t)(n0 + r) * 256 + ks * 64) * 2 + kb,
              Bs + (w * 4 + i) * 1024);
    }
    __syncthreads();
#pragma unroll
    for (int kk = 0; kk < 2; ++kk) {
      bf16x8 af[4], bfr[4];
#pragma unroll
      for (int t4 = 0; t4 < 4; ++t4) {
        af[t4]  = *(const bf16x8*)(As + (wr * 64 + t4 * 16 + c) * 128 + kk * 64 + s4 * 16);
        bfr[t4] = *(const bf16x8*)(Bs + (wc * 64 + t4 * 16 + c) * 128 + kk * 64 + s4 * 16);
      }
#pragma unroll
      for (int mt = 0; mt < 4; ++mt)
#pragma unroll
        for (int nt = 0; nt < 4; ++nt)
          acc[mt][nt] = mfma16(af[mt], bfr[nt], acc[mt][nt]);
    }
  }

#pragma unroll
  for (int nt = 0; nt < 4; ++nt) {
    int col = n0 + wc * 64 + nt * 16 + c;
    float bpv = bp[col];
#pragma unroll
    for (int mt = 0; mt < 4; ++mt)
#pragma unroll
      for (int q = 0; q < 4; ++q) {
        int row = m0 + wr * 64 + mt * 16 + s4 * 4 + q;
        out[(size_t)row * 256 + col] = acc[mt][nt][q] + bpv;
      }
  }
}

// ---------------------------------------------------------------------------
extern "C" void kernel_launch(void* const* d_in, const int* in_sizes, int n_in,
                              void* d_out, int out_size, void* d_ws, size_t ws_size,
                              hipStream_t stream)
{
  const float* x     = (const float*)d_in[0];
  const float* wq    = (const float*)d_in[1];
  const float* bq    = (const float*)d_in[2];
  const float* wkv   = (const float*)d_in[3];
  const float* bkv   = (const float*)d_in[4];
  const float* table = (const float*)d_in[5];
  const float* wp    = (const float*)d_in[6];
  const float* bp    = (const float*)d_in[7];
  float* out = (float*)d_out;
  char* ws = (char*)d_ws;

  u16*   attnout = (u16*)(ws + WSB_OFF);
  u16*   wqkvT   = (u16*)(ws + WQKVT_OFF);
  u16*   wpT     = (u16*)(ws + WPT_OFF);
  float* biasf   = (float*)(ws + BIAS_OFF);

  prep_kernel<<<1152, 256, 0, stream>>>(wq, wkv, wp, table, wqkvT, wpT, biasf);
  kf_kernel<<<NWIN, 256, 0, stream>>>(x, wqkvT, bq, bkv, biasf, attnout);
  proj_kernel<<<4096, 256, 0, stream>>>(attnout, wpT, bp, out);
}

// Round 2
// 394.298 us; speedup vs baseline: 1.6130x; 1.6130x over previous
//
#include <hip/hip_runtime.h>

typedef unsigned short u16;
typedef __attribute__((ext_vector_type(8))) __bf16 bf16x8;
typedef __attribute__((ext_vector_type(4))) float f32x4;

#define SCALE 0.17677669529663687f

// workspace layout (bytes)
#define ATTN_OFF   0ull              // attn-out bf16 [4096*64][256] : 134217728
#define WSTORE_OFF 134217728ull      // [8][4][96][64] bf16 pre-swz  : 393216
#define WPT_OFF    134610944ull      // [256][256] bf16, linear      : 131072
#define BIASF_OFF  134742016ull      // [8][64][64] f32              : 131072

__device__ __forceinline__ u16 f2bf(float f) {
  __bf16 h = (__bf16)f;
  return __builtin_bit_cast(u16, h);
}

__device__ __forceinline__ void gload16(const void* g, void* l) {
  __builtin_amdgcn_global_load_lds(
      (const __attribute__((address_space(1))) unsigned int*)g,
      (__attribute__((address_space(3))) unsigned int*)l, 16, 0, 0);
}

__device__ __forceinline__ f32x4 mfma16(bf16x8 a, bf16x8 b, f32x4 c) {
  return __builtin_amdgcn_mfma_f32_16x16x32_bf16(a, b, c, 0, 0, 0);
}

// ---------------------------------------------------------------------------
// prep: Wstore = head-major permuted wqkv, bf16, SCALE baked into q-cols,
// XOR-swizzle ((col&7)<<4 on the 128B k-row) baked in so the fused kernel's
// linear global_load_lds + swizzled ds_read_b128 is bank-uniform.
// Layout: [h][ks(4)][col(96)][64 bf16].  Also wpT (linear) and biasf gather.
// ---------------------------------------------------------------------------
__global__ __launch_bounds__(256) void prep_kernel(
    const float* __restrict__ wq, const float* __restrict__ wkv,
    const float* __restrict__ wp, const float* __restrict__ table,
    u16* __restrict__ Wstore, u16* __restrict__ wpT, float* __restrict__ biasf)
{
  int i = blockIdx.x * 256 + threadIdx.x;
  if (i < 196608) {                      // Wstore
    int h = i / 24576, r = i % 24576;
    int ks = r / 6144, r2 = r % 6144;
    int col = r2 / 64, wi = r2 % 64;
    int kl = ((wi * 2) ^ ((col & 7) << 4)) >> 1;   // logical k within step
    int k = ks * 64 + kl;
    int n = (col < 32) ? h * 32 + col
          : (col < 64) ? 256 + h * 32 + (col - 32)
                       : 512 + h * 32 + (col - 64);
    float v = (n < 256) ? wq[k * 256 + n] : wkv[k * 512 + (n - 256)];
    if (col < 32) v *= SCALE;
    Wstore[i] = f2bf(v);
  } else if (i < 262144) {               // wpT [n][k]
    int j = i - 196608;
    int n = j >> 8, k = j & 255;
    wpT[n * 256 + k] = f2bf(wp[k * 256 + n]);
  } else if (i < 294912) {               // biasf [h][n][m]
    int j = i - 262144;
    int h = j >> 12, n = (j >> 6) & 63, m = j & 63;
    int dr = (n >> 3) - (m >> 3) + 7;
    int dc = (n & 7) - (m & 7) + 7;
    biasf[j] = table[(dr * 15 + dc) * 8 + h];
  }
}

// ---------------------------------------------------------------------------
// fused kernel: 1 window/block, 4 waves, 48.6 KB LDS -> 3 blocks/CU.
// x held in registers as A-fragments (loaded once). Per head h:
//   GEMM qkv_h = x @ Wh^T (M64 x N96 x K256, BK=64, dbuf LDS weight tiles,
//   waves 2Mx2N) -> epilogue writes q[64][32],k[64][32] (stride 80) and
//   vT[32][64] (stride 144) to LDS -> S=QK^T+bias, wave-parallel softmax
//   (16 q-rows/wave) -> P[64][64] (stride 144) -> O=P@V -> global bf16.
// ---------------------------------------------------------------------------
__global__ __launch_bounds__(256, 3) void kf_kernel(
    const float* __restrict__ x, const u16* __restrict__ Wstore,
    const float* __restrict__ bq, const float* __restrict__ bkv,
    const float* __restrict__ biasf, u16* __restrict__ attnout)
{
  __shared__ char smem[48640];
  char* Wt = smem;              // 2 x [96][128B] = 24576
  char* Qb = smem + 24576;      // [64][80B]  (32 bf16 + pad)
  char* Kb = smem + 29696;      // [64][80B]
  char* Vb = smem + 34816;      // [32][144B] (64 bf16 + pad) = vT
  char* Pb = smem + 39424;      // [64][144B]

  const int tid  = threadIdx.x;
  const int lane = tid & 63;
  const int w    = tid >> 6;
  const int c    = lane & 15;
  const int s4   = lane >> 4;
  const int wr   = w >> 1;      // GEMM row-half
  const int wc   = w & 1;       // GEMM col-half
  const int b    = blockIdx.x;
  const f32x4 fzero = {0.f, 0.f, 0.f, 0.f};

  // ---- x -> register A-fragments: xf[mr][kc] covers rows wr*32+mr*16, K=256
  bf16x8 xf[2][8];
  {
    const float* xw = x + (size_t)b * 16384;
#pragma unroll
    for (int mr = 0; mr < 2; ++mr) {
      int t = wr * 32 + mr * 16 + c;
#pragma unroll
      for (int kc = 0; kc < 8; ++kc) {
        const float* p = xw + t * 256 + kc * 32 + s4 * 8;
        float4 v0 = *(const float4*)p;
        float4 v1 = *(const float4*)(p + 4);
        bf16x8 f;
        f[0] = (__bf16)v0.x; f[1] = (__bf16)v0.y;
        f[2] = (__bf16)v0.z; f[3] = (__bf16)v0.w;
        f[4] = (__bf16)v1.x; f[5] = (__bf16)v1.y;
        f[6] = (__bf16)v1.z; f[7] = (__bf16)v1.w;
        xf[mr][kc] = f;
      }
    }
  }

  // ---- weight stage: tile n = h*4+ks is 12288 B, linear copy via gload_lds
  const char* wsrc = (const char*)Wstore;
#define STAGE(n, bufi)                                                   \
  {                                                                      \
    const char* _s = wsrc + (size_t)(n) * 12288 + w * 1024 + lane * 16;  \
    char* _d = Wt + (bufi) * 12288 + w * 1024;                           \
    gload16(_s, _d);                                                     \
    gload16(_s + 4096, _d + 4096);                                       \
    gload16(_s + 8192, _d + 8192);                                       \
  }

  STAGE(0, 0);
  __syncthreads();

#pragma unroll 1
  for (int h = 0; h < 8; ++h) {
    // ---- GEMM: qkv_h = x @ Wh^T ----
    f32x4 acc[2][3];
#pragma unroll
    for (int mr = 0; mr < 2; ++mr)
#pragma unroll
      for (int nc = 0; nc < 3; ++nc) acc[mr][nc] = fzero;

#pragma unroll
    for (int ks = 0; ks < 4; ++ks) {
      int nxt = h * 4 + ks + 1;
      if (nxt < 32) STAGE(nxt, (ks + 1) & 1);
      const char* bb = Wt + (ks & 1) * 12288;
#pragma unroll
      for (int kk = 0; kk < 2; ++kk) {
        bf16x8 bfr[3];
#pragma unroll
        for (int nc = 0; nc < 3; ++nc) {
          int col = wc * 48 + nc * 16 + c;
          int off = col * 128 + ((kk * 64 + s4 * 16) ^ ((col & 7) << 4));
          bfr[nc] = *(const bf16x8*)(bb + off);
        }
#pragma unroll
        for (int mr = 0; mr < 2; ++mr)
#pragma unroll
          for (int nc = 0; nc < 3; ++nc)
            acc[mr][nc] = mfma16(xf[mr][ks * 2 + kk], bfr[nc], acc[mr][nc]);
      }
      __syncthreads();
    }

    // ---- epilogue: +bias, write q/k (stride 80) and vT (transposed, 144)
#pragma unroll
    for (int nc = 0; nc < 3; ++nc) {
      int col = wc * 48 + nc * 16 + c;
      float bias = (col < 32) ? bq[h * 32 + col] * SCALE
                 : (col < 64) ? bkv[h * 32 + (col - 32)]
                              : bkv[256 + h * 32 + (col - 64)];
#pragma unroll
      for (int mr = 0; mr < 2; ++mr)
#pragma unroll
        for (int q = 0; q < 4; ++q) {
          int t = wr * 32 + mr * 16 + s4 * 4 + q;
          u16 val = f2bf(acc[mr][nc][q] + bias);
          if (col < 32)      *(u16*)(Qb + t * 80 + col * 2) = val;
          else if (col < 64) *(u16*)(Kb + t * 80 + (col - 32) * 2) = val;
          else               *(u16*)(Vb + (col - 64) * 144 + t * 2) = val;
        }
    }
    __syncthreads();

    // ---- S = Q K^T + bias (wave w owns q-rows w*16..w*16+16) ----
    bf16x8 aq = *(const bf16x8*)(Qb + (w * 16 + c) * 80 + s4 * 16);
    f32x4 sa[4];
#pragma unroll
    for (int nt = 0; nt < 4; ++nt) {
      bf16x8 bk = *(const bf16x8*)(Kb + (nt * 16 + c) * 80 + s4 * 16);
      sa[nt] = mfma16(aq, bk, fzero);
    }

    float sb[4][4];   // [q][nt]
#pragma unroll
    for (int q = 0; q < 4; ++q) {
      int t = w * 16 + s4 * 4 + q;
      const float* bt = biasf + h * 4096 + t * 64 + c;
#pragma unroll
      for (int nt = 0; nt < 4; ++nt) sb[q][nt] = sa[nt][q] + bt[nt * 16];
    }

    // ---- softmax + P write ----
#pragma unroll
    for (int q = 0; q < 4; ++q) {
      float mx = fmaxf(fmaxf(sb[q][0], sb[q][1]), fmaxf(sb[q][2], sb[q][3]));
      mx = fmaxf(mx, __shfl_xor(mx, 1));
      mx = fmaxf(mx, __shfl_xor(mx, 2));
      mx = fmaxf(mx, __shfl_xor(mx, 4));
      mx = fmaxf(mx, __shfl_xor(mx, 8));
      float s0 = 0.f;
#pragma unroll
      for (int nt = 0; nt < 4; ++nt) {
        float p = __expf(sb[q][nt] - mx);
        sb[q][nt] = p;
        s0 += p;
      }
      s0 += __shfl_xor(s0, 1);
      s0 += __shfl_xor(s0, 2);
      s0 += __shfl_xor(s0, 4);
      s0 += __shfl_xor(s0, 8);
      float inv = __builtin_amdgcn_rcpf(s0);
      int t = w * 16 + s4 * 4 + q;
#pragma unroll
      for (int nt = 0; nt < 4; ++nt)
        *(u16*)(Pb + t * 144 + (nt * 16 + c) * 2) = f2bf(sb[q][nt] * inv);
    }
    __syncthreads();

    // ---- O = P @ V (via vT), rows w*16..+16, d = 32 ----
    f32x4 oa[2] = {fzero, fzero};
#pragma unroll
    for (int kk = 0; kk < 2; ++kk) {
      bf16x8 ap = *(const bf16x8*)(Pb + (w * 16 + c) * 144 + kk * 64 + s4 * 16);
#pragma unroll
      for (int d2 = 0; d2 < 2; ++d2) {
        bf16x8 bv = *(const bf16x8*)(Vb + (d2 * 16 + c) * 144 + kk * 64 + s4 * 16);
        oa[d2] = mfma16(ap, bv, oa[d2]);
      }
    }
    u16* ow = attnout + (size_t)b * 16384 + h * 32;
#pragma unroll
    for (int d2 = 0; d2 < 2; ++d2)
#pragma unroll
      for (int q = 0; q < 4; ++q) {
        int t = w * 16 + s4 * 4 + q;
        ow[t * 256 + d2 * 16 + c] = f2bf(oa[d2][q]);
      }
  }
#undef STAGE
}

// ---------------------------------------------------------------------------
// output projection: out = attnout(bf16) @ wp + bp, fp32 out.
// 128x128 tile, BK=64, global_load_lds staging, 4 waves 2x2. (unchanged)
// ---------------------------------------------------------------------------
__global__ __launch_bounds__(256) void proj_kernel(
    const u16* __restrict__ A, const u16* __restrict__ wpT,
    const float* __restrict__ bp, float* __restrict__ out)
{
  __shared__ char smem[32768];
  char* As = smem;
  char* Bs = smem + 16384;
  const int tid = threadIdx.x, lane = tid & 63, w = tid >> 6;
  const int c = lane & 15, s4 = lane >> 4;
  const int m0 = (int)(blockIdx.x >> 1) * 128;
  const int n0 = (int)(blockIdx.x & 1) * 128;
  const int wr = w >> 1, wc = w & 1;
  const f32x4 fzero = {0.f, 0.f, 0.f, 0.f};

  f32x4 acc[4][4];
#pragma unroll
  for (int mt = 0; mt < 4; ++mt)
#pragma unroll
    for (int nt = 0; nt < 4; ++nt) acc[mt][nt] = fzero;

  for (int ks = 0; ks < 4; ++ks) {
    __syncthreads();
#pragma unroll
    for (int i = 0; i < 4; ++i) {
      int o = (w * 4 + i) * 1024 + lane * 16;
      int r = o >> 7, kb = o & 127;
      gload16((const char*)A + ((size_t)(m0 + r) * 256 + ks * 64) * 2 + kb,
              As + (w * 4 + i) * 1024);
      gload16((const char*)wpT + ((size_t)(n0 + r) * 256 + ks * 64) * 2 + kb,
              Bs + (w * 4 + i) * 1024);
    }
    __syncthreads();
#pragma unroll
    for (int kk = 0; kk < 2; ++kk) {
      bf16x8 af[4], bfr[4];
#pragma unroll
      for (int t4 = 0; t4 < 4; ++t4) {
        af[t4]  = *(const bf16x8*)(As + (wr * 64 + t4 * 16 + c) * 128 + kk * 64 + s4 * 16);
        bfr[t4] = *(const bf16x8*)(Bs + (wc * 64 + t4 * 16 + c) * 128 + kk * 64 + s4 * 16);
      }
#pragma unroll
      for (int mt = 0; mt < 4; ++mt)
#pragma unroll
        for (int nt = 0; nt < 4; ++nt)
          acc[mt][nt] = mfma16(af[mt], bfr[nt], acc[mt][nt]);
    }
  }

#pragma unroll
  for (int nt = 0; nt < 4; ++nt) {
    int col = n0 + wc * 64 + nt * 16 + c;
    float bpv = bp[col];
#pragma unroll
    for (int mt = 0; mt < 4; ++mt)
#pragma unroll
      for (int q = 0; q < 4; ++q) {
        int row = m0 + wr * 64 + mt * 16 + s4 * 4 + q;
        out[(size_t)row * 256 + col] = acc[mt][nt][q] + bpv;
      }
  }
}

// ---------------------------------------------------------------------------
extern "C" void kernel_launch(void* const* d_in, const int* in_sizes, int n_in,
                              void* d_out, int out_size, void* d_ws, size_t ws_size,
                              hipStream_t stream)
{
  const float* x     = (const float*)d_in[0];
  const float* wq    = (const float*)d_in[1];
  const float* bq    = (const float*)d_in[2];
  const float* wkv   = (const float*)d_in[3];
  const float* bkv   = (const float*)d_in[4];
  const float* table = (const float*)d_in[5];
  const float* wp    = (const float*)d_in[6];
  const float* bp    = (const float*)d_in[7];
  float* out = (float*)d_out;
  char* ws = (char*)d_ws;

  u16*   attnout = (u16*)(ws + ATTN_OFF);
  u16*   Wstore  = (u16*)(ws + WSTORE_OFF);
  u16*   wpT     = (u16*)(ws + WPT_OFF);
  float* biasf   = (float*)(ws + BIASF_OFF);

  prep_kernel<<<1152, 256, 0, stream>>>(wq, wkv, wp, table, Wstore, wpT, biasf);
  kf_kernel<<<4096, 256, 0, stream>>>(x, Wstore, bq, bkv, biasf, attnout);
  proj_kernel<<<4096, 256, 0, stream>>>(attnout, wpT, bp, out);
}